// Round 1
// 346.587 us; speedup vs baseline: 1.1026x; 1.1026x over previous
//
#include <hip/hip_runtime.h>
#include <math.h>

// Problem constants (from reference)
#define NWAY   10
#define DIMD   64
#define HWN    49           // H*W = 7*7
#define NSUP   800          // N_WAY*K_SHOT*PRJ
#define NQRY   16000        // N_WAY*Q_QUERY*PRJ
#define NTRI   2080         // 64*65/2
#define FEAT_PER (DIMD*HWN) // 3136 floats per sample
#define LDST   68           // fp32 dcov row stride (bank rotation, 16B-aligned)
#define KPAD   72           // bf16 row stride: 144 B/row -> 4-bank rotation,
                            // 16B-aligned fragment reads, balanced b128 access
#define STP    12           // transposed support row stride (floats): 48 B, 16B-aligned

typedef __attribute__((ext_vector_type(8))) short bf16x8;
typedef __attribute__((ext_vector_type(4))) float f32x4;

struct __align__(16) BDCShared {
    union {
        float dcov[DIMD*LDST];                 // 17408 B (sqrt'd BDC matrix)
        unsigned short hl[2*DIMD*KPAD];        // 18432 B: H[64][72], L[64][72]
    } u;
    float dg[DIMD];
    float rm[DIMD];
    float w4[4];            // per-wave partial for tm
    float red[4*12];        // per-wave partials: 10 cross + 1 qq
};

// Map linear triu index k -> (i,j), j>=i, row-major triu of 64x64 (init only).
__device__ __forceinline__ void k2ij(int k, int& io, int& jo) {
    int ii = (int)floorf((129.0f - sqrtf(16641.0f - 8.0f*(float)k)) * 0.5f);
    int off = ii*(129-ii)/2;
    if (off > k) { --ii; off = ii*(129-ii)/2; }
    else {
        int off2 = (ii+1)*(128-ii)/2;
        if (off2 <= k) { ii += 1; off = off2; }
    }
    io = ii;
    jo = ii + (k - off);
}

// HW packed bf16 convert (RNE): r.lo16 = bf16(a), r.hi16 = bf16(b)
__device__ __forceinline__ unsigned cvt_pk_bf16(float a, float b) {
    unsigned r;
    asm("v_cvt_pk_bf16_f32 %0, %1, %2" : "=v"(r) : "v"(a), "v"(b));
    return r;
}

// MFMA-based BDC: writes sqrt'd dcov (uncentered) into sm.u.dcov, row means
// into sm.rm, returns total mean. Block = 256 threads = 4 waves.
__device__ __forceinline__ float bdc_compute(const float* __restrict__ feat,
                                             float et, int sample,
                                             BDCShared& sm) {
    const int tid = threadIdx.x;
    unsigned short* Hh = sm.u.hl;
    unsigned short* Lh = sm.u.hl + DIMD*KPAD;

    // ---- Stage: row-mapped. Thread owns (row d, quarter hq): 16 contiguous k.
    // No div, pad folded in (hq==3 covers k=48..63, zeros beyond 48).
    // cvt_pk pairs + 4x ds_write_b128 per thread (vs ~25 ds_write_b16 before).
    {
        const int d = tid & 63, hq = tid >> 6;       // hq is wave-uniform
        const float* rowp = feat + (size_t)sample * FEAT_PER + d*HWN + hq*16;
        float x[16];
        if (hq < 3) {
            #pragma unroll
            for (int i = 0; i < 16; ++i) x[i] = rowp[i];
        } else {
            x[0] = rowp[0];                          // k = 48
            #pragma unroll
            for (int i = 1; i < 16; ++i) x[i] = 0.0f;
        }
        unsigned hp[8], lp[8];
        #pragma unroll
        for (int i = 0; i < 8; ++i) {
            unsigned h = cvt_pk_bf16(x[2*i], x[2*i+1]);
            float h0 = __uint_as_float(h << 16);
            float h1 = __uint_as_float(h & 0xffff0000u);
            hp[i] = h;
            lp[i] = cvt_pk_bf16(x[2*i] - h0, x[2*i+1] - h1);
        }
        uint4* hd = (uint4*)&Hh[d*KPAD + hq*16];     // 144d+32hq B: 16B-aligned
        uint4* ld = (uint4*)&Lh[d*KPAD + hq*16];
        hd[0] = make_uint4(hp[0], hp[1], hp[2], hp[3]);
        hd[1] = make_uint4(hp[4], hp[5], hp[6], hp[7]);
        ld[0] = make_uint4(lp[0], lp[1], lp[2], lp[3]);
        ld[1] = make_uint4(lp[4], lp[5], lp[6], lp[7]);
    }
    __syncthreads();

    // ---- Gram via MFMA 16x16x32 bf16. Wave w owns G rows 16w..16w+15.
    const int wv = tid >> 6, lane = tid & 63;
    const int qd = lane >> 4, c15 = lane & 15;
    const int abase = (16*wv + c15)*KPAD + qd*8;
    bf16x8 AH0 = *(const bf16x8*)&Hh[abase];
    bf16x8 AH1 = *(const bf16x8*)&Hh[abase + 32];
    bf16x8 AL0 = *(const bf16x8*)&Lh[abase];
    bf16x8 AL1 = *(const bf16x8*)&Lh[abase + 32];

    f32x4 acc[4];
    #pragma unroll
    for (int J = 0; J < 4; ++J) {
        const int bbase = (16*J + c15)*KPAD + qd*8;
        bf16x8 BH0 = *(const bf16x8*)&Hh[bbase];
        bf16x8 BH1 = *(const bf16x8*)&Hh[bbase + 32];
        bf16x8 BL0 = *(const bf16x8*)&Lh[bbase];
        bf16x8 BL1 = *(const bf16x8*)&Lh[bbase + 32];
        f32x4 a = {0.f, 0.f, 0.f, 0.f};
        a = __builtin_amdgcn_mfma_f32_16x16x32_bf16(AH0, BH0, a, 0, 0, 0);
        a = __builtin_amdgcn_mfma_f32_16x16x32_bf16(AH1, BH1, a, 0, 0, 0);
        a = __builtin_amdgcn_mfma_f32_16x16x32_bf16(AL0, BH0, a, 0, 0, 0);
        a = __builtin_amdgcn_mfma_f32_16x16x32_bf16(AL1, BH1, a, 0, 0, 0);
        a = __builtin_amdgcn_mfma_f32_16x16x32_bf16(AH0, BL0, a, 0, 0, 0);
        a = __builtin_amdgcn_mfma_f32_16x16x32_bf16(AH1, BL1, a, 0, 0, 0);
        acc[J] = a;
    }

    // ---- dg from G diagonal (tile J == wv). C/D: col=lane&15, row=quad*4+reg.
    #pragma unroll
    for (int J = 0; J < 4; ++J) {
        if (J == wv) {
            #pragma unroll
            for (int r = 0; r < 4; ++r)
                if (c15 == 4*qd + r) sm.dg[16*wv + c15] = acc[J][r];
        }
    }
    __syncthreads();   // dg visible; all frag reads done -> union reuse safe

    // ---- Fused dcov: sqrt'd values kept in regs; transposed b128 writes
    // (valid: G and dcov are symmetric); row sums reduced in-register.
    float* dcov = sm.u.dcov;
    f32x4 dgi = *(const f32x4*)&sm.dg[16*wv + 4*qd];
    float rs0 = 0.f, rs1 = 0.f, rs2 = 0.f, rs3 = 0.f;
    #pragma unroll
    for (int J = 0; J < 4; ++J) {
        float dgj = sm.dg[16*J + c15];
        f32x4 o;
        #pragma unroll
        for (int r = 0; r < 4; ++r) {
            float t2 = fmaf(-2.0f, acc[J][r], dgi[r] + dgj);
            t2 = fmaxf(t2, 0.0f);
            o[r] = __builtin_amdgcn_sqrtf(fmaf(et, t2, 1e-5f));
        }
        rs0 += o[0]; rs1 += o[1]; rs2 += o[2]; rs3 += o[3];
        // write (i_base..i_base+3, j) at transposed position [j][i_base..]:
        // full coverage + symmetry => dcov holds the full matrix.
        *(f32x4*)&dcov[(16*J + c15)*LDST + 16*wv + 4*qd] = o;
    }
    // reduce row sums over the 16 j-lanes of each group
    #pragma unroll
    for (int o = 1; o < 16; o <<= 1) {
        rs0 += __shfl_xor(rs0, o, 64);
        rs1 += __shfl_xor(rs1, o, 64);
        rs2 += __shfl_xor(rs2, o, 64);
        rs3 += __shfl_xor(rs3, o, 64);
    }
    if (c15 == 0) {
        f32x4 rmv = {rs0*(1.0f/64.0f), rs1*(1.0f/64.0f),
                     rs2*(1.0f/64.0f), rs3*(1.0f/64.0f)};
        *(f32x4*)&sm.rm[16*wv + 4*qd] = rmv;
    }
    float tt = (rs0 + rs1) + (rs2 + rs3);
    tt += __shfl_xor(tt, 16, 64);
    tt += __shfl_xor(tt, 32, 64);
    if (lane == 0) sm.w4[wv] = tt;
    __syncthreads();   // dcov + rm + w4 visible
    return (sm.w4[0] + sm.w4[1] + sm.w4[2] + sm.w4[3]) * (1.0f/4096.0f);
}

// init: build triu table (addr<<16 | i<<8 | j), zero s2 + loss slot
__global__ void kern_init(unsigned* __restrict__ table,
                          float* __restrict__ s2,
                          float* __restrict__ loss_slot) {
    int i = blockIdx.x * 256 + threadIdx.x;
    if (i < NTRI) {
        int ii, jj; k2ij(i, ii, jj);
        table[i] = ((unsigned)(ii*LDST + jj) << 16) | ((unsigned)ii << 8) | (unsigned)jj;
    }
    if (i < NWAY) s2[i] = 0.0f;
    if (i == 0) loss_slot[0] = 0.0f;
}

// Support: BDC -> raw centered triu vector scattered to global (NO atomics).
__global__ __launch_bounds__(256, 6) void kern_support(const float* __restrict__ feat,
                                                       const float* __restrict__ temp,
                                                       const unsigned* __restrict__ table,
                                                       float* __restrict__ tvout) {
    __shared__ BDCShared sm;
    float et = __expf(temp[0]);
    int s = blockIdx.x;                 // 0..799
    float tm = bdc_compute(feat, et, s, sm);
    float* dst = tvout + (size_t)s * NTRI;
    for (int k = threadIdx.x; k < NTRI; k += 256) {
        unsigned t = table[k];
        dst[k] = sm.u.dcov[t >> 16] - sm.rm[(t >> 8) & 63] - sm.rm[t & 63] + tm;
    }
}

// Deterministic reduce: prototype means (transposed [k][12]) + s2.
// Grid = NWAY * 9 blocks; block (m, kc) handles k in [kc*256, kc*256+256).
__global__ __launch_bounds__(256) void kern_reduce(const float* __restrict__ tv,
                                                   float* __restrict__ supT,
                                                   float* __restrict__ s2) {
    __shared__ float red[4];
    int m = blockIdx.x / 9, kc = blockIdx.x % 9;
    int k = kc*256 + threadIdx.x;
    float S = 0.0f;
    if (k < NTRI) {
        const float* p = tv + (size_t)(80*m) * NTRI + k;
        float a0 = 0.f, a1 = 0.f, a2 = 0.f, a3 = 0.f;
        for (int s4 = 0; s4 < 80; s4 += 4) {
            a0 += p[(size_t)(s4+0)*NTRI];
            a1 += p[(size_t)(s4+1)*NTRI];
            a2 += p[(size_t)(s4+2)*NTRI];
            a3 += p[(size_t)(s4+3)*NTRI];
        }
        S = ((a0+a1)+(a2+a3)) * (1.0f/80.0f);
        supT[k*STP + m] = S;
    }
    float ps = S * S;   // 0 for k >= NTRI
    int lane = threadIdx.x & 63, wv = threadIdx.x >> 6;
    #pragma unroll
    for (int o = 32; o > 0; o >>= 1) ps += __shfl_xor(ps, o, 64);
    if (lane == 0) red[wv] = ps;
    __syncthreads();
    if (threadIdx.x == 0) atomicAdd(&s2[m], red[0]+red[1]+red[2]+red[3]);
}

// Query: BDC -> score_m = -(qq + s2[m] - 2*cross[m])  (reference's own form)
__global__ __launch_bounds__(256, 6) void kern_query(const float* __restrict__ feat,
                                                     const float* __restrict__ temp,
                                                     const unsigned* __restrict__ table,
                                                     const float* __restrict__ supT,
                                                     const float* __restrict__ s2,
                                                     float* __restrict__ out) {
    __shared__ BDCShared sm;
    float et = __expf(temp[0]);
    int qn = blockIdx.x;                // 0..15999
    float tm = bdc_compute(feat, et, NSUP + qn, sm);

    float qq = 0.0f;
    float cr[NWAY];
    #pragma unroll
    for (int m = 0; m < NWAY; ++m) cr[m] = 0.0f;

    for (int k = threadIdx.x; k < NTRI; k += 256) {
        unsigned t = table[k];
        float v = sm.u.dcov[t >> 16] - sm.rm[(t >> 8) & 63] - sm.rm[t & 63] + tm;
        qq = fmaf(v, v, qq);
        const float4* sp = (const float4*)(supT + (size_t)k * STP);
        float4 sa = sp[0], sb = sp[1], sc = sp[2];   // cols 10,11 are pad (unused)
        cr[0] = fmaf(v, sa.x, cr[0]);
        cr[1] = fmaf(v, sa.y, cr[1]);
        cr[2] = fmaf(v, sa.z, cr[2]);
        cr[3] = fmaf(v, sa.w, cr[3]);
        cr[4] = fmaf(v, sb.x, cr[4]);
        cr[5] = fmaf(v, sb.y, cr[5]);
        cr[6] = fmaf(v, sb.z, cr[6]);
        cr[7] = fmaf(v, sb.w, cr[7]);
        cr[8] = fmaf(v, sc.x, cr[8]);
        cr[9] = fmaf(v, sc.y, cr[9]);
    }

    // reduce 11 accumulators: wave butterfly + cross-wave via LDS
    int lane = threadIdx.x & 63, wv = threadIdx.x >> 6;
    #pragma unroll
    for (int m = 0; m < NWAY; ++m) {
        float v = cr[m];
        #pragma unroll
        for (int o = 32; o > 0; o >>= 1) v += __shfl_xor(v, o, 64);
        cr[m] = v;
    }
    #pragma unroll
    for (int o = 32; o > 0; o >>= 1) qq += __shfl_xor(qq, o, 64);
    if (lane == 0) {
        #pragma unroll
        for (int m = 0; m < NWAY; ++m) sm.red[wv*12 + m] = cr[m];
        sm.red[wv*12 + 10] = qq;
    }
    __syncthreads();
    if (threadIdx.x < NWAY) {
        int m = threadIdx.x;
        float CR = sm.red[m] + sm.red[12+m] + sm.red[24+m] + sm.red[36+m];
        float QQ = sm.red[10] + sm.red[22] + sm.red[34] + sm.red[46];
        out[(size_t)qn * NWAY + m] = -(QQ + s2[m] - 2.0f*CR);
    }
}

// Softmax NLL partials: one atomicAdd per block.
__global__ __launch_bounds__(256) void kern_loss(const float* __restrict__ score,
                                                 const int* __restrict__ label,
                                                 float* __restrict__ loss_out) {
    __shared__ float red[4];
    int n = blockIdx.x * 256 + threadIdx.x;
    float lsum = 0.0f;
    if (n < NQRY) {
        const float* srow = score + (size_t)n * NWAY;
        float s[NWAY];
        float mx = -1e30f;
        #pragma unroll
        for (int m = 0; m < NWAY; ++m) { s[m] = srow[m]; mx = fmaxf(mx, s[m]); }
        float se = 0.0f;
        #pragma unroll
        for (int m = 0; m < NWAY; ++m) se += __expf(s[m] - mx);
        float lse = mx + __logf(se);
        lsum = lse - s[label[n]];
    }
    int lane = threadIdx.x & 63, wv = threadIdx.x >> 6;
    #pragma unroll
    for (int o = 32; o > 0; o >>= 1) lsum += __shfl_xor(lsum, o, 64);
    if (lane == 0) red[wv] = lsum;
    __syncthreads();
    if (threadIdx.x == 0)
        atomicAdd(loss_out, (red[0] + red[1] + red[2] + red[3]) * (1.0f / (float)NQRY));
}

extern "C" void kernel_launch(void* const* d_in, const int* in_sizes, int n_in,
                              void* d_out, int out_size, void* d_ws, size_t ws_size,
                              hipStream_t stream) {
    const float* feat = (const float*)d_in[0];
    const float* temp = (const float*)d_in[1];
    const int*   label = (const int*)d_in[2];
    float* out = (float*)d_out;

    // workspace layout (~6.8 MB):
    float*    tv    = (float*)d_ws;                  // 800*2080 f = 6.656 MB
    float*    supT  = tv + (size_t)NSUP * NTRI;      // 2080*12 f (transposed+pad)
    float*    s2    = supT + NTRI*STP;               // 10 f (+pad)
    unsigned* table = (unsigned*)(s2 + 16);          // 2080 u32
    float* loss_slot = out + (size_t)NQRY * NWAY;

    kern_init<<<(NTRI + 255)/256, 256, 0, stream>>>(table, s2, loss_slot);
    kern_support<<<NSUP, 256, 0, stream>>>(feat, temp, table, tv);
    kern_reduce<<<NWAY*9, 256, 0, stream>>>(tv, supT, s2);
    kern_query<<<NQRY, 256, 0, stream>>>(feat, temp, table, supT, s2, out);
    kern_loss<<<(NQRY + 255)/256, 256, 0, stream>>>(out, label, loss_slot);
}